// Round 2
// 133.243 us; speedup vs baseline: 1.0465x; 1.0465x over previous
//
#include <hip/hip_runtime.h>
#include <stdint.h>

typedef unsigned short u16;
typedef unsigned int u32;
typedef __bf16 bf16x8 __attribute__((ext_vector_type(8)));
typedef unsigned short u16x8 __attribute__((ext_vector_type(8)));
typedef unsigned short u16x4 __attribute__((ext_vector_type(4)));
typedef float f32x4 __attribute__((ext_vector_type(4)));
typedef float f32x16 __attribute__((ext_vector_type(16)));

#define MFMA16(a, b, c) __builtin_amdgcn_mfma_f32_16x16x32_bf16((a), (b), (c), 0, 0, 0)
#define MFMA32(a, b, c) __builtin_amdgcn_mfma_f32_32x32x16_bf16((a), (b), (c), 0, 0, 0)

__device__ __forceinline__ u16 f2b(float f) {
    union { unsigned int i; float f; } v; v.f = f;
    unsigned int r = (v.i + 0x7FFFu + ((v.i >> 16) & 1u)) >> 16;
    return (u16)r;
}
__device__ __forceinline__ u32 pk2(float lo, float hi) {
    return (u32)f2b(lo) | ((u32)f2b(hi) << 16);
}
// async global->LDS, 16B per lane. HW dest = wave-uniform base + lane*16,
// which matches our wave-linear per-lane pointers.
__device__ __forceinline__ void gload16(const void* g, void* l) {
    __builtin_amdgcn_global_load_lds(
        (const __attribute__((address_space(1))) u32*)g,
        (__attribute__((address_space(3))) u32*)l, 16, 0, 0);
}

constexpr int N = 4096;
constexpr int Cc = 128;
constexpr int Fc = 128;
constexpr int BATCH = 4;
constexpr int NT = N / 128;     // 32 key tiles

constexpr int XS_STRIDE = 136;
constexpr int WT_STRIDE = 136;
constexpr int OM_STRIDE = 130;  // epilogue merge rows (f32): 2-way banks = free

// ---------------------------------------------------------------------------
// W pre-transpose: Wt[which][f][c] (bf16). grid 3 x 256.
// ---------------------------------------------------------------------------
__global__ __launch_bounds__(256) void wtrans_kernel(
    const float* __restrict__ Wq, const float* __restrict__ Wk,
    const float* __restrict__ Wv, u16* __restrict__ WtG)
{
    __shared__ __align__(16) u16 Wl[128 * 132];  // [c][f]
    const int tid = threadIdx.x;
    const int which = blockIdx.x;
    const float* W = which == 0 ? Wq : (which == 1 ? Wk : Wv);
#pragma unroll
    for (int it = 0; it < 16; ++it) {
        int idx4 = tid + it * 256; int e0 = idx4 * 4;
        int c = e0 >> 7, f = e0 & 127;
        float4 wv = *(const float4*)(W + e0);
        u16x4 h; h[0] = f2b(wv.x); h[1] = f2b(wv.y); h[2] = f2b(wv.z); h[3] = f2b(wv.w);
        *(u16x4*)&Wl[c * 132 + f] = h;
    }
    __syncthreads();
    u16* out = WtG + which * 16384;
#pragma unroll
    for (int it = 0; it < 8; ++it) {
        int idx8 = tid + it * 256; int e0 = idx8 * 8;
        int f = e0 >> 7, c = e0 & 127;
        u16x8 h;
#pragma unroll
        for (int j = 0; j < 8; ++j) h[j] = Wl[(c + j) * 132 + f];
        *(u16x8*)(out + e0) = h;
    }
}

// ---------------------------------------------------------------------------
// Projection (fp32 X, bf16 Wt -> bf16 workspace). grid (64,3,4) x 256.
// K and Vt are stored CHUNK-SWIZZLED for the attn kernel's conflict-free
// swizzled ds_read_b128 with linear global_load_lds staging:
//   K  : element (row, c)  stored at c ^ ((row&7)<<3)        [u16 units]
//   Vt : element (f, key)  stored at key ^ ((f&7)<<3)        [within 64-key window]
// Q stays linear (read straight into registers by attn).
// ---------------------------------------------------------------------------
__global__ __launch_bounds__(256) void proj_kernel(
    const float* __restrict__ q_in, const float* __restrict__ kv_in,
    const u16* __restrict__ WtG,
    const float* __restrict__ bq, const float* __restrict__ bk,
    const float* __restrict__ bv,
    u16* __restrict__ Qw, u16* __restrict__ Kw, u16* __restrict__ Vtw)
{
    __shared__ __align__(16) u16 Xs[64 * XS_STRIDE];   // [m][c] bf16
    __shared__ __align__(16) u16 Wt[128 * WT_STRIDE];  // [f][c] bf16

    const int tid = threadIdx.x;
    const int which = blockIdx.y;
    const int b = blockIdx.z;
    const int m0 = blockIdx.x * 64;

    const float* X = (which == 0 ? q_in : kv_in) + ((size_t)b * N + m0) * Cc;
    const u16* Wsrc = WtG + which * 16384;
    const float* bias = which == 0 ? bq : (which == 1 ? bk : bv);

#pragma unroll
    for (int it = 0; it < 8; ++it) {
        int idx4 = tid + it * 256; int e0 = idx4 * 4;
        int r = e0 >> 7, c = e0 & 127;
        float4 xv = *(const float4*)(X + e0);
        u16x4 h; h[0] = f2b(xv.x); h[1] = f2b(xv.y); h[2] = f2b(xv.z); h[3] = f2b(xv.w);
        *(u16x4*)&Xs[r * XS_STRIDE + c] = h;
    }
#pragma unroll
    for (int it = 0; it < 8; ++it) {
        int idx8 = tid + it * 256; int e0 = idx8 * 8;
        int f = e0 >> 7, c = e0 & 127;
        *(u16x8*)&Wt[f * WT_STRIDE + c] = *(const u16x8*)(Wsrc + e0);
    }
    __syncthreads();

    const int lane = tid & 63;
    const int w = tid >> 6;
    const int n16 = lane & 15;
    const int quad = lane >> 4;

    if (which < 2) {
        bf16x8 ax[4];
#pragma unroll
        for (int kk = 0; kk < 4; ++kk)
            ax[kk] = *(const bf16x8*)&Xs[(w * 16 + n16) * XS_STRIDE + kk * 32 + quad * 8];
        const float scale = (which == 0) ? 0.08838834764831845f : 1.0f;
        const int swmask = (which == 1) ? 7 : 0;   // swizzle only K
        u16* Out = (which == 0) ? Qw : Kw;
#pragma unroll
        for (int ft = 0; ft < 8; ++ft) {
            f32x4 acc = {0.f, 0.f, 0.f, 0.f};
#pragma unroll
            for (int kk = 0; kk < 4; ++kk) {
                bf16x8 bw = *(const bf16x8*)&Wt[(ft * 16 + n16) * WT_STRIDE + kk * 32 + quad * 8];
                acc = MFMA16(ax[kk], bw, acc);
            }
            float bias_f = bias[ft * 16 + n16];
#pragma unroll
            for (int r = 0; r < 4; ++r) {
                int row = m0 + w * 16 + quad * 4 + r;
                int f = ft * 16 + n16;
                int fs = f ^ ((row & swmask) << 3);
                Out[((size_t)b * N + row) * Fc + fs] = f2b((acc[r] + bias_f) * scale);
            }
        }
    } else {
#pragma unroll
        for (int ft2 = 0; ft2 < 2; ++ft2) {
            int ftg = w * 2 + ft2;
            bf16x8 aw[4];
#pragma unroll
            for (int kk = 0; kk < 4; ++kk)
                aw[kk] = *(const bf16x8*)&Wt[(ftg * 16 + n16) * WT_STRIDE + kk * 32 + quad * 8];
            float bias4[4];
#pragma unroll
            for (int r = 0; r < 4; ++r) bias4[r] = bias[ftg * 16 + quad * 4 + r];
#pragma unroll
            for (int nt = 0; nt < 4; ++nt) {
                f32x4 acc = {0.f, 0.f, 0.f, 0.f};
#pragma unroll
                for (int kk = 0; kk < 4; ++kk) {
                    bf16x8 bx = *(const bf16x8*)&Xs[(nt * 16 + n16) * XS_STRIDE + kk * 32 + quad * 8];
                    acc = MFMA16(aw[kk], bx, acc);
                }
#pragma unroll
                for (int r = 0; r < 4; ++r) {
                    int fg = ftg * 16 + quad * 4 + r;
                    int rowg = m0 + nt * 16 + n16;
                    int rs = rowg ^ ((fg & 7) << 3);
                    Vtw[((size_t)b * Fc + fg) * N + rs] = f2b(acc[r] + bias4[r]);
                }
            }
        }
    }
}

// ---------------------------------------------------------------------------
// Flash attention, 32x32 MFMA, in-register P (permlane32_swap), dbuf
// global_load_lds staging, 1 barrier/tile, atomic-free 4-slot LDS merge.
// 512 threads = 8 waves = 2 q-groups(32 rows) x 4 key-groups(32 keys).
// grid (64, 4), LDS ~131 KB (1 block/CU). XCD-swizzled: one batch per XCD.
// ---------------------------------------------------------------------------
__global__ __launch_bounds__(512, 2) void attn_kernel(
    const u16* __restrict__ Qw, const u16* __restrict__ Kw,
    const u16* __restrict__ Vtw, float* __restrict__ out)
{
    __shared__ __align__(16) char smem[134144];
    u16* const Ks0 = (u16*)smem;                 // [128 key][128 c], swizzled chunks
    u16* const Ks1 = (u16*)(smem + 32768);
    u16* const Vs0 = (u16*)(smem + 65536);       // [128 ch][128 key], swizzled chunks
    u16* const Vs1 = (u16*)(smem + 98304);

    const int tid = threadIdx.x;
    // XCD-aware remap: blocks with equal (id&7) share a batch ->
    // K+V working set 2 MB <= 4 MB per-XCD L2.
    const int id = blockIdx.x + 64 * blockIdx.y;
    const int b = (id >> 1) & 3;
    const int q0 = (((id & 1) << 5) + (id >> 3)) << 6;

    const int lane = tid & 63;
    const int w = tid >> 6;      // 0..7
    const int kg = w & 3;        // 32-key group within 128-key tile
    const int qg = w >> 2;       // 32-row q group within 64-row block
    const int l31 = lane & 31;
    const int hi = lane >> 5;

    // ---- Q fragments (B-operand of swapped QK^T), held for whole loop
    bf16x8 aq[8];
    {
        const u16* qp = Qw + ((size_t)b * N + q0 + qg * 32 + l31) * Cc + hi * 8;
#pragma unroll
        for (int kk = 0; kk < 8; ++kk) aq[kk] = *(const bf16x8*)(qp + kk * 16);
    }

    const u16* const Kb = Kw + (size_t)b * N * Cc;
    const u16* const Vb = Vtw + (size_t)b * Fc * N;

    // ---- loop-invariant swizzled LDS read offsets (u16 units)
    const int rk = kg * 32 + l31;
    const int swk = (rk & 7) << 3;
    int koff[8];
#pragma unroll
    for (int kk = 0; kk < 8; ++kk)
        koff[kk] = rk * 128 + (((kk * 2 + hi) * 8) ^ swk);
    int voff[4][2];
#pragma unroll
    for (int cb = 0; cb < 4; ++cb) {
        int rv = cb * 32 + l31;
        int swv = (rv & 7) << 3;
#pragma unroll
        for (int ks = 0; ks < 2; ++ks)
            voff[cb][ks] = rv * 128 + (((kg * 4 + ks * 2 + hi) * 8) ^ swv);
    }

    f32x16 o[4];
#pragma unroll
    for (int cb = 0; cb < 4; ++cb)
#pragma unroll
        for (int i = 0; i < 16; ++i) o[cb][i] = 0.f;
    float lloc = 0.f;

    int ci[4];
#pragma unroll
    for (int it = 0; it < 4; ++it) ci[it] = tid + it * 512;

    auto STAGE = [&](u16* kd, u16* vd, int t) {
        const u16* ksrc = Kb + (size_t)t * (128 * 128);   // K tile is contiguous
        const u16* vsrc = Vb + t * 128;
#pragma unroll
        for (int it = 0; it < 4; ++it) {
            gload16(ksrc + ci[it] * 8, kd + ci[it] * 8);
            gload16(vsrc + (size_t)(ci[it] >> 4) * N + (ci[it] & 15) * 8, vd + ci[it] * 8);
        }
    };

    auto TILE_STEP = [&](const u16* Ksb, const u16* Vsb) {
        // S^T = K . Q^T over this wave's 32 keys: D[key][q], col=q=l31
        f32x16 st;
#pragma unroll
        for (int i = 0; i < 16; ++i) st[i] = 0.f;
#pragma unroll
        for (int kk = 0; kk < 8; ++kk) {
            bf16x8 ak = *(const bf16x8*)(Ksb + koff[kk]);
            st = MFMA32(ak, aq[kk], st);
        }
        // p = exp(s); reg i holds key (i&3)+8*(i>>2)+4*hi (+16 for i>=8)
        float p[16];
#pragma unroll
        for (int i = 0; i < 16; ++i) p[i] = __expf(st[i]);
        lloc += ((((p[0] + p[1]) + (p[2] + p[3])) + ((p[4] + p[5]) + (p[6] + p[7])))
               + (((p[8] + p[9]) + (p[10] + p[11])) + ((p[12] + p[13]) + (p[14] + p[15]))));
        // pack to bf16 pairs + permlane32_swap -> PV B-fragments (P^T), no LDS
        bf16x8 pb[2];
#pragma unroll
        for (int ks = 0; ks < 2; ++ks) {
            u32 a0 = pk2(p[ks * 8 + 0], p[ks * 8 + 1]);
            u32 a1 = pk2(p[ks * 8 + 2], p[ks * 8 + 3]);
            u32 a2 = pk2(p[ks * 8 + 4], p[ks * 8 + 5]);
            u32 a3 = pk2(p[ks * 8 + 6], p[ks * 8 + 7]);
            auto s02 = __builtin_amdgcn_permlane32_swap(a0, a2, false, false);
            auto s13 = __builtin_amdgcn_permlane32_swap(a1, a3, false, false);
            union { u32 u[4]; bf16x8 v; } bb;
            bb.u[0] = s02[0]; bb.u[1] = s13[0]; bb.u[2] = s02[1]; bb.u[3] = s13[1];
            pb[ks] = bb.v;
        }
        // O^T += Vt . P^T : D[ch][q], A = Vt rows (swizzled b128 reads)
#pragma unroll
        for (int cb = 0; cb < 4; ++cb) {
#pragma unroll
            for (int ks = 0; ks < 2; ++ks) {
                bf16x8 av = *(const bf16x8*)(Vsb + voff[cb][ks]);
                o[cb] = MFMA32(av, pb[ks], o[cb]);
            }
        }
    };

    STAGE(Ks0, Vs0, 0);
    __syncthreads();                      // drains vmcnt -> tile 0 resident
    for (int t = 0; t < NT; t += 2) {
        if (t + 1 < NT) STAGE(Ks1, Vs1, t + 1);   // in flight under compute
        TILE_STEP(Ks0, Vs0);
        __syncthreads();                  // vmcnt(0)+barrier: tile t+1 ready
        if (t + 2 < NT) STAGE(Ks0, Vs0, t + 2);
        TILE_STEP(Ks1, Vs1);
        __syncthreads();
    }

    // ---- atomic-free merge: all 8 waves dump to private slot, then reduce
    float lv = lloc + __shfl_xor(lloc, 32);   // full l-partial for q=l31, this kg

    float* const Om = (float*)smem;            // [4 kg][64 q][OM_STRIDE] f32
    float* const Lm = (float*)(smem + 4 * 64 * OM_STRIDE * 4);  // [4 kg][64 q]

    const int qrow_w = qg * 32 + l31;          // 0..63 within block
    const int crow0 = 4 * hi;
    {
        float* dst = Om + (size_t)(kg * 64 + qrow_w) * OM_STRIDE;
#pragma unroll
        for (int cb = 0; cb < 4; ++cb)
#pragma unroll
            for (int i = 0; i < 16; ++i) {
                int ch = cb * 32 + (i & 3) + 8 * (i >> 2) + crow0;
                dst[ch] = o[cb][i];
            }
        if (hi == 0) Lm[kg * 64 + qrow_w] = lv;
    }
    __syncthreads();

    const int qrow = tid >> 3;                // 0..63
    const int ch0 = (tid & 7) * 16;
    const float lsum = Lm[qrow] + Lm[64 + qrow] + Lm[128 + qrow] + Lm[192 + qrow];
    const float linv = 1.0f / lsum;
    float* op = out + ((size_t)b * N + q0 + qrow) * Fc + ch0;
#pragma unroll
    for (int j4 = 0; j4 < 4; ++j4) {
        f32x4 v;
#pragma unroll
        for (int jj = 0; jj < 4; ++jj) {
            int ch = ch0 + j4 * 4 + jj;
            float s = Om[(size_t)(0 * 64 + qrow) * OM_STRIDE + ch]
                    + Om[(size_t)(1 * 64 + qrow) * OM_STRIDE + ch]
                    + Om[(size_t)(2 * 64 + qrow) * OM_STRIDE + ch]
                    + Om[(size_t)(3 * 64 + qrow) * OM_STRIDE + ch];
            v[jj] = s * linv;
        }
        *(f32x4*)(op + j4 * 4) = v;
    }
}

extern "C" void kernel_launch(void* const* d_in, const int* in_sizes, int n_in,
                              void* d_out, int out_size, void* d_ws, size_t ws_size,
                              hipStream_t stream) {
    (void)in_sizes; (void)n_in; (void)out_size; (void)ws_size;
    const float* q_in  = (const float*)d_in[0];
    const float* kv_in = (const float*)d_in[1];
    const float* Wq = (const float*)d_in[2];
    const float* bq = (const float*)d_in[3];
    const float* Wk = (const float*)d_in[4];
    const float* bk = (const float*)d_in[5];
    const float* Wv = (const float*)d_in[6];
    const float* bv = (const float*)d_in[7];

    const size_t qkv = (size_t)BATCH * N * Fc;
    u16* Qw  = (u16*)d_ws;          // [b][m][f] bf16, pre-scaled by 1/sqrt(F)
    u16* Kw  = Qw + qkv;            // [b][m][f] bf16, chunk-swizzled
    u16* Vtw = Kw + qkv;            // [b][f][m] bf16, chunk-swizzled
    u16* WtG = Vtw + qkv;           // [3][f][c] bf16 pre-transposed weights

    wtrans_kernel<<<dim3(3), dim3(256), 0, stream>>>(Wq, Wk, Wv, WtG);
    proj_kernel<<<dim3(64, 3, BATCH), dim3(256), 0, stream>>>(
        q_in, kv_in, WtG, bq, bk, bv, Qw, Kw, Vtw);
    attn_kernel<<<dim3(64, BATCH), dim3(512), 0, stream>>>(
        Qw, Kw, Vtw, (float*)d_out);
}